// Round 9
// baseline (503.677 us; speedup 1.0000x reference)
//
#include <hip/hip_runtime.h>

#define CDIM 128
#define HDIM 512
#define NB 2
#define NNODES 50000
#define NEDGES 800000
#define ROWS (NB * NNODES)

typedef _Float16 half8 __attribute__((ext_vector_type(8)));
typedef _Float16 half4 __attribute__((ext_vector_type(4)));
typedef float f32x4 __attribute__((ext_vector_type(4)));

__device__ __forceinline__ f32x4 mfma_f16(half8 a, half8 b, f32x4 c) {
  return __builtin_amdgcn_mfma_f32_16x16x32_f16(a, b, c, 0, 0, 0);
}

#define GLOAD_LDS16(g, l)                                                      \
  __builtin_amdgcn_global_load_lds(                                            \
      (const __attribute__((address_space(1))) void*)(g),                      \
      (__attribute__((address_space(3))) void*)(l), 16, 0, 0)

// ---------------- CSR build ----------------
__global__ void hist_k(const int* __restrict__ ei, int* __restrict__ counts) {
  int e = blockIdx.x * 256 + threadIdx.x;
  if (e < NEDGES) atomicAdd(&counts[ei[NEDGES + e]], 1);
}

#define SC_BLOCKS 13

__global__ __launch_bounds__(256) void scan1_k(const int* __restrict__ counts,
                                               int* __restrict__ bsum) {
  __shared__ int ws[4];
  int i0 = blockIdx.x * 4096 + threadIdx.x * 16;
  int s = 0;
#pragma unroll
  for (int k = 0; k < 16; ++k) {
    int i = i0 + k;
    s += (i < NNODES) ? counts[i] : 0;
  }
#pragma unroll
  for (int off = 1; off < 64; off <<= 1) s += __shfl_down(s, off);
  if ((threadIdx.x & 63) == 0) ws[threadIdx.x >> 6] = s;
  __syncthreads();
  if (threadIdx.x == 0) bsum[blockIdx.x] = ws[0] + ws[1] + ws[2] + ws[3];
}

__global__ void scan2_k(const int* __restrict__ bsum, int* __restrict__ bbase,
                        int* __restrict__ offsets) {
  int run = 0;
  for (int b = 0; b < SC_BLOCKS; ++b) {
    bbase[b] = run;
    run += bsum[b];
  }
  offsets[NNODES] = run;
}

__global__ __launch_bounds__(256) void scan3_k(const int* __restrict__ counts,
                                               const int* __restrict__ bbase,
                                               int* __restrict__ offsets,
                                               int* __restrict__ cursor) {
  __shared__ int sm[256];
  int i0 = blockIdx.x * 4096 + threadIdx.x * 16;
  int v[16];
  int tsum = 0;
#pragma unroll
  for (int k = 0; k < 16; ++k) {
    int i = i0 + k;
    v[k] = (i < NNODES) ? counts[i] : 0;
    tsum += v[k];
  }
  sm[threadIdx.x] = tsum;
  __syncthreads();
  for (int off = 1; off < 256; off <<= 1) {
    int t = (threadIdx.x >= off) ? sm[threadIdx.x - off] : 0;
    __syncthreads();
    sm[threadIdx.x] += t;
    __syncthreads();
  }
  int run = bbase[blockIdx.x] + sm[threadIdx.x] - tsum;
#pragma unroll
  for (int k = 0; k < 16; ++k) {
    int i = i0 + k;
    if (i < NNODES) {
      offsets[i] = run;
      cursor[i] = run;
    }
    run += v[k];
  }
}

__global__ void fill_k(const int* __restrict__ ei, int* __restrict__ cursor,
                       int* __restrict__ col) {
  int e = blockIdx.x * 256 + threadIdx.x;
  if (e < NEDGES) {
    int d = ei[NEDGES + e];
    int p = atomicAdd(&cursor[d], 1);
    col[p] = ei[e];
  }
}

// ---- fp32 [b][n][c] -> fp16 batch-interleaved [n][b][c] ----
__global__ void cvt16i_k(const float* __restrict__ s, _Float16* __restrict__ d) {
  const int PB = NNODES * CDIM;
  int i = blockIdx.x * 256 + threadIdx.x;
  int str = gridDim.x * 256;
  for (; i < ROWS * (CDIM / 8); i += str) {
    size_t flat = (size_t)i * 8;
    int b = (int)(flat / PB);
    size_t r = flat - (size_t)b * PB;
    int n = (int)(r >> 7);
    int c0 = (int)(r & 127);
    float4 f0 = *(const float4*)(s + flat);
    float4 f1 = *(const float4*)(s + flat + 4);
    half8 o;
    o[0] = (_Float16)f0.x; o[1] = (_Float16)f0.y;
    o[2] = (_Float16)f0.z; o[3] = (_Float16)f0.w;
    o[4] = (_Float16)f1.x; o[5] = (_Float16)f1.y;
    o[6] = (_Float16)f1.z; o[7] = (_Float16)f1.w;
    *(half8*)(d + ((size_t)n * 2 + b) * CDIM + c0) = o;
  }
}

// ---------------- weight pre-pack into per-chunk merged fragment layout ------
__global__ void pack_mlp(const float* __restrict__ W1, const float* __restrict__ W2,
                         _Float16* __restrict__ dst) {
  int tid = blockIdx.x * 256 + threadIdx.x;  // 0..16383
  if (tid >= 16384) return;
  int l = tid & 63;
  int g = (tid >> 6) & 7;
  int c = (tid >> 9) & 15;
  int isW2 = tid >> 13;
  int lg = l >> 4, l15 = l & 15;
  _Float16* o;
  if (!isW2) {
    int jt = g >> 2, ks = g & 3;
    int k0 = ks * 32 + lg * 8;
    int n = c * 32 + jt * 16 + l15;
    o = dst + (size_t)c * 8192 + g * 512 + l * 8;
#pragma unroll
    for (int i = 0; i < 8; ++i) o[i] = (_Float16)W1[(size_t)(k0 + i) * HDIM + n];
  } else {
    int k0 = c * 32 + lg * 8;
    int n = g * 16 + l15;
    o = dst + (size_t)c * 8192 + 4096 + g * 512 + l * 8;
#pragma unroll
    for (int i = 0; i < 8; ++i) o[i] = (_Float16)W2[(size_t)(k0 + i) * CDIM + n];
  }
}

// ------- fused agg + MLP: block = 64 node-pairs (128 interleaved rows) -------
// Phase A: each wave privately aggregates its own 16 nodes -> LDS h-slice.
// Phase B: A-frags from LDS, then the W-staged double-buffered MFMA loop.
template <typename OT, bool REMAP>
__global__ __launch_bounds__(256, 2) void fused_k(
    const _Float16* __restrict__ x, const int* __restrict__ offs,
    const int* __restrict__ col, const _Float16* __restrict__ wpk,
    const float* __restrict__ b1, const float* __restrict__ b2,
    OT* __restrict__ out) {
  __shared__ alignas(16) _Float16 htile[4][16 * 256];  // 32 KB, per-wave slices
  __shared__ alignas(16) _Float16 wbuf[2][8192];       // 32 KB dbuf
  __shared__ alignas(16) _Float16 tbuf[4][32 * 32];    // 8 KB

  const int tidx = threadIdx.x;
  const int lane = tidx & 63;
  const int wid = tidx >> 6;
  const int l15 = lane & 15, lg = lane >> 4;
  const long long r0 = (long long)blockIdx.x * 128 + wid * 32;
  const int nb = blockIdx.x * 64 + wid * 16;  // this wave's first node

  // prefetch W chunk 0 (hides under phase A)
  {
    const _Float16* src = wpk;
#pragma unroll
    for (int q = 0; q < 4; ++q) {
      int s = wid * 4 + q;
      GLOAD_LDS16(src + s * 512 + lane * 8, &wbuf[0][s * 512]);
    }
  }

  // ---- phase A: aggregate 16 node-pairs (wave-private, no barrier) ----
  const half4* xp = (const half4*)x;
  _Float16* hw = &htile[wid][0];
  for (int i = 0; i < 16; ++i) {
    int node = nb + i;
    half4 r = (half4){0, 0, 0, 0};
    if (node < NNODES) {
      half4 self = xp[(size_t)node * 64 + lane];
      float a0 = (float)self[0], a1 = (float)self[1];
      float a2 = (float)self[2], a3 = (float)self[3];
      float c0 = 0.f, c1 = 0.f, c2 = 0.f, c3 = 0.f;
      int e = offs[node], e1 = offs[node + 1];
      for (; e + 3 < e1; e += 4) {
        int s0 = col[e], s1 = col[e + 1], s2 = col[e + 2], s3 = col[e + 3];
        half4 v0 = xp[(size_t)s0 * 64 + lane];
        half4 v1 = xp[(size_t)s1 * 64 + lane];
        half4 v2 = xp[(size_t)s2 * 64 + lane];
        half4 v3 = xp[(size_t)s3 * 64 + lane];
        a0 += (float)v0[0] + (float)v1[0];
        a1 += (float)v0[1] + (float)v1[1];
        a2 += (float)v0[2] + (float)v1[2];
        a3 += (float)v0[3] + (float)v1[3];
        c0 += (float)v2[0] + (float)v3[0];
        c1 += (float)v2[1] + (float)v3[1];
        c2 += (float)v2[2] + (float)v3[2];
        c3 += (float)v2[3] + (float)v3[3];
      }
      for (; e < e1; ++e) {
        half4 v0 = xp[(size_t)col[e] * 64 + lane];
        a0 += (float)v0[0];
        a1 += (float)v0[1];
        a2 += (float)v0[2];
        a3 += (float)v0[3];
      }
      r[0] = (_Float16)(a0 + c0);
      r[1] = (_Float16)(a1 + c1);
      r[2] = (_Float16)(a2 + c2);
      r[3] = (_Float16)(a3 + c3);
    }
    *(half4*)&hw[i * 256 + lane * 4] = r;
  }

  // ---- A-fragments from the wave's own LDS slice (once) ----
  half8 A[2][4];
#pragma unroll
  for (int rt = 0; rt < 2; ++rt) {
    int rl = rt * 16 + l15;
    const _Float16* hp = hw + (rl >> 1) * 256 + (rl & 1) * 128 + lg * 8;
#pragma unroll
    for (int ks = 0; ks < 4; ++ks) A[rt][ks] = *(const half8*)(hp + ks * 32);
  }

  __syncthreads();  // W chunk 0 staged (vmcnt drained), all waves ready

  f32x4 acc[2][8];
#pragma unroll
  for (int rt = 0; rt < 2; ++rt)
#pragma unroll
    for (int ct = 0; ct < 8; ++ct) acc[rt][ct] = (f32x4){0.f, 0.f, 0.f, 0.f};

  _Float16* tw = &tbuf[wid][0];

  for (int c = 0; c < 16; ++c) {
    const int cur = c & 1;
    if (c + 1 < 16) {
      const _Float16* src = wpk + (size_t)(c + 1) * 8192;
#pragma unroll
      for (int q = 0; q < 4; ++q) {
        int s = wid * 4 + q;
        GLOAD_LDS16(src + s * 512 + lane * 8, &wbuf[cur ^ 1][s * 512]);
      }
    }
    const _Float16* w1c = &wbuf[cur][0];
    const _Float16* w2c = &wbuf[cur][4096];

#pragma unroll
    for (int jt = 0; jt < 2; ++jt) {
      f32x4 t0 = (f32x4){0.f, 0.f, 0.f, 0.f};
      f32x4 t1 = (f32x4){0.f, 0.f, 0.f, 0.f};
#pragma unroll
      for (int ks = 0; ks < 4; ++ks) {
        half8 b = *(const half8*)(w1c + (jt * 4 + ks) * 512 + lane * 8);
        t0 = mfma_f16(A[0][ks], b, t0);
        t1 = mfma_f16(A[1][ks], b, t1);
      }
      float bb = b1[c * 32 + jt * 16 + l15];
      int j = jt * 16 + l15;
#pragma unroll
      for (int r = 0; r < 4; ++r) {
        int n0 = lg * 4 + r;
        tw[n0 * 32 + (j ^ (((n0 >> 2) & 3) << 3))] = (_Float16)fmaxf(t0[r] + bb, 0.f);
        int n1 = 16 + lg * 4 + r;
        tw[n1 * 32 + (j ^ (((n1 >> 2) & 3) << 3))] = (_Float16)fmaxf(t1[r] + bb, 0.f);
      }
    }

    half8 ta0, ta1;
    {
      int n = l15;
      ta0 = *(const half8*)(tw + n * 32 + ((lg * 8) ^ (((n >> 2) & 3) << 3)));
      n = 16 + l15;
      ta1 = *(const half8*)(tw + n * 32 + ((lg * 8) ^ (((n >> 2) & 3) << 3)));
    }
#pragma unroll
    for (int ct = 0; ct < 8; ++ct) {
      half8 b = *(const half8*)(w2c + ct * 512 + lane * 8);
      acc[0][ct] = mfma_f16(ta0, b, acc[0][ct]);
      acc[1][ct] = mfma_f16(ta1, b, acc[1][ct]);
    }
    __syncthreads();
  }

#pragma unroll
  for (int ct = 0; ct < 8; ++ct) {
    float b2v = b2[ct * 16 + l15];
#pragma unroll
    for (int rt = 0; rt < 2; ++rt) {
#pragma unroll
      for (int r = 0; r < 4; ++r) {
        long long g = r0 + rt * 16 + lg * 4 + r;
        if (g < ROWS) {
          size_t off;
          if (REMAP) {
            off = (size_t)(g & 1) * NNODES * CDIM + (size_t)(g >> 1) * CDIM + ct * 16 + l15;
          } else {
            off = (size_t)g * CDIM + ct * 16 + l15;
          }
          out[off] = (OT)(acc[rt][ct][r] + b2v);
        }
      }
    }
  }
}

extern "C" void kernel_launch(void* const* d_in, const int* in_sizes, int n_in,
                              void* d_out, int out_size, void* d_ws, size_t ws_size,
                              hipStream_t stream) {
  const float* x0 = (const float*)d_in[0];
  const int* ei = (const int*)d_in[1];
  const float* W1_0 = (const float*)d_in[2];
  const float* b1_0 = (const float*)d_in[3];
  const float* W2_0 = (const float*)d_in[4];
  const float* b2_0 = (const float*)d_in[5];
  const float* W1_1 = (const float*)d_in[6];
  const float* b1_1 = (const float*)d_in[7];
  const float* W2_1 = (const float*)d_in[8];
  const float* b2_1 = (const float*)d_in[9];
  float* out = (float*)d_out;

  // workspace layout
  _Float16* xh = (_Float16*)d_ws;                  // ROWS*CDIM interleaved (25.6 MB)
  _Float16* hh = xh + (size_t)ROWS * CDIM;         // ROWS*CDIM interleaved (25.6 MB)
  _Float16* wpk0 = hh + (size_t)ROWS * CDIM;       // 131072 halfs
  _Float16* wpk1 = wpk0 + 131072;                  // 131072 halfs
  int* counts = (int*)(wpk1 + 131072);             // N
  int* offsets = counts + NNODES;                  // N+1
  int* cursor = offsets + NNODES + 1;              // N
  int* col = cursor + NNODES;                      // E
  int* bsum = col + NEDGES;                        // 16
  int* bbase = bsum + 16;                          // 16

  const int eBlocks = (NEDGES + 255) / 256;
  const int fusedBlocks = (NNODES + 63) / 64;  // 782

  // CSR build
  hipMemsetAsync(counts, 0, NNODES * sizeof(int), stream);
  hist_k<<<eBlocks, 256, 0, stream>>>(ei, counts);
  scan1_k<<<SC_BLOCKS, 256, 0, stream>>>(counts, bsum);
  scan2_k<<<1, 1, 0, stream>>>(bsum, bbase, offsets);
  scan3_k<<<SC_BLOCKS, 256, 0, stream>>>(counts, bbase, offsets, cursor);
  fill_k<<<eBlocks, 256, 0, stream>>>(ei, cursor, col);

  // weight pre-pack
  pack_mlp<<<64, 256, 0, stream>>>(W1_0, W2_0, wpk0);
  pack_mlp<<<64, 256, 0, stream>>>(W1_1, W2_1, wpk1);

  // x -> fp16 interleaved
  cvt16i_k<<<2048, 256, 0, stream>>>(x0, xh);

  // layer 0 fused: agg(xh)+mlp -> hh (fp16, interleaved)
  fused_k<_Float16, false><<<fusedBlocks, 256, 0, stream>>>(
      xh, offsets, col, wpk0, b1_0, b2_0, hh);
  // layer 1 fused: agg(hh)+mlp -> out (fp32, [b][n][c])
  fused_k<float, true><<<fusedBlocks, 256, 0, stream>>>(
      hh, offsets, col, wpk1, b1_1, b2_1, out);
}

// Round 10
// 320.655 us; speedup vs baseline: 1.5708x; 1.5708x over previous
//
#include <hip/hip_runtime.h>

#define CDIM 128
#define HDIM 512
#define NB 2
#define NNODES 50000
#define NEDGES 800000
#define ROWS (NB * NNODES)
#define EBLOCKS ((NEDGES + 255) / 256)  // 3125
#define CVTBLOCKS 2048

typedef _Float16 half8 __attribute__((ext_vector_type(8)));
typedef _Float16 half4 __attribute__((ext_vector_type(4)));
typedef float f32x4 __attribute__((ext_vector_type(4)));

__device__ __forceinline__ f32x4 mfma_f16(half8 a, half8 b, f32x4 c) {
  return __builtin_amdgcn_mfma_f32_16x16x32_f16(a, b, c, 0, 0, 0);
}

#define GLOAD_LDS16(g, l)                                                      \
  __builtin_amdgcn_global_load_lds(                                            \
      (const __attribute__((address_space(1))) void*)(g),                      \
      (__attribute__((address_space(3))) void*)(l), 16, 0, 0)

// ---- merged: edge histogram + fp32->fp16 interleaved convert ----
__global__ __launch_bounds__(256) void histcvt_k(const int* __restrict__ ei,
                                                 int* __restrict__ counts,
                                                 const float* __restrict__ s,
                                                 _Float16* __restrict__ d) {
  if (blockIdx.x < EBLOCKS) {
    int e = blockIdx.x * 256 + threadIdx.x;
    if (e < NEDGES) atomicAdd(&counts[ei[NEDGES + e]], 1);
  } else {
    const int PB = NNODES * CDIM;
    int i = (blockIdx.x - EBLOCKS) * 256 + threadIdx.x;
    int str = CVTBLOCKS * 256;
    for (; i < ROWS * (CDIM / 8); i += str) {
      size_t flat = (size_t)i * 8;
      int b = (int)(flat / PB);
      size_t r = flat - (size_t)b * PB;
      int n = (int)(r >> 7);
      int c0 = (int)(r & 127);
      float4 f0 = *(const float4*)(s + flat);
      float4 f1 = *(const float4*)(s + flat + 4);
      half8 o;
      o[0] = (_Float16)f0.x; o[1] = (_Float16)f0.y;
      o[2] = (_Float16)f0.z; o[3] = (_Float16)f0.w;
      o[4] = (_Float16)f1.x; o[5] = (_Float16)f1.y;
      o[6] = (_Float16)f1.z; o[7] = (_Float16)f1.w;
      *(half8*)(d + ((size_t)n * 2 + b) * CDIM + c0) = o;
    }
  }
}

#define SC_BLOCKS 13

__global__ __launch_bounds__(256) void scan1_k(const int* __restrict__ counts,
                                               int* __restrict__ bsum) {
  __shared__ int ws[4];
  int i0 = blockIdx.x * 4096 + threadIdx.x * 16;
  int s = 0;
#pragma unroll
  for (int k = 0; k < 16; ++k) {
    int i = i0 + k;
    s += (i < NNODES) ? counts[i] : 0;
  }
#pragma unroll
  for (int off = 1; off < 64; off <<= 1) s += __shfl_down(s, off);
  if ((threadIdx.x & 63) == 0) ws[threadIdx.x >> 6] = s;
  __syncthreads();
  if (threadIdx.x == 0) bsum[blockIdx.x] = ws[0] + ws[1] + ws[2] + ws[3];
}

// merged scan2+scan3: each block derives its own base from bsum
__global__ __launch_bounds__(256) void scan23_k(const int* __restrict__ counts,
                                                const int* __restrict__ bsum,
                                                int* __restrict__ offsets,
                                                int* __restrict__ cursor) {
  __shared__ int sm[256];
  int bb = 0;
  for (int b = 0; b < (int)blockIdx.x; ++b) bb += bsum[b];
  int i0 = blockIdx.x * 4096 + threadIdx.x * 16;
  int v[16];
  int tsum = 0;
#pragma unroll
  for (int k = 0; k < 16; ++k) {
    int i = i0 + k;
    v[k] = (i < NNODES) ? counts[i] : 0;
    tsum += v[k];
  }
  sm[threadIdx.x] = tsum;
  __syncthreads();
  for (int off = 1; off < 256; off <<= 1) {
    int t = (threadIdx.x >= off) ? sm[threadIdx.x - off] : 0;
    __syncthreads();
    sm[threadIdx.x] += t;
    __syncthreads();
  }
  int run = bb + sm[threadIdx.x] - tsum;
#pragma unroll
  for (int k = 0; k < 16; ++k) {
    int i = i0 + k;
    if (i < NNODES) {
      offsets[i] = run;
      cursor[i] = run;
    }
    run += v[k];
  }
  if (blockIdx.x == SC_BLOCKS - 1 && threadIdx.x == 255) offsets[NNODES] = bb + sm[255];
}

__global__ void fill_k(const int* __restrict__ ei, int* __restrict__ cursor,
                       int* __restrict__ col) {
  int e = blockIdx.x * 256 + threadIdx.x;
  if (e < NEDGES) {
    int d = ei[NEDGES + e];
    int p = atomicAdd(&cursor[d], 1);
    col[p] = ei[e];
  }
}

// ---- aggregation: one wave per node-pair; 8-edge unroll, 2 accum chains ----
__global__ __launch_bounds__(256) void aggi_k(const _Float16* __restrict__ x,
                                              const int* __restrict__ offs,
                                              const int* __restrict__ col,
                                              _Float16* __restrict__ h) {
  int node = blockIdx.x * 4 + (threadIdx.x >> 6);
  int lane = threadIdx.x & 63;
  if (node >= NNODES) return;
  const half4* xp = (const half4*)x;
  half4 self = xp[(size_t)node * 64 + lane];
  float a0 = (float)self[0], a1 = (float)self[1], a2 = (float)self[2], a3 = (float)self[3];
  float c0 = 0.f, c1 = 0.f, c2 = 0.f, c3 = 0.f;
  int e = offs[node], e1 = offs[node + 1];
  for (; e + 7 < e1; e += 8) {
    int s0 = col[e], s1 = col[e + 1], s2 = col[e + 2], s3 = col[e + 3];
    int s4 = col[e + 4], s5 = col[e + 5], s6 = col[e + 6], s7 = col[e + 7];
    half4 v0 = xp[(size_t)s0 * 64 + lane];
    half4 v1 = xp[(size_t)s1 * 64 + lane];
    half4 v2 = xp[(size_t)s2 * 64 + lane];
    half4 v3 = xp[(size_t)s3 * 64 + lane];
    half4 v4 = xp[(size_t)s4 * 64 + lane];
    half4 v5 = xp[(size_t)s5 * 64 + lane];
    half4 v6 = xp[(size_t)s6 * 64 + lane];
    half4 v7 = xp[(size_t)s7 * 64 + lane];
    a0 += (float)v0[0] + (float)v1[0] + (float)v2[0] + (float)v3[0];
    a1 += (float)v0[1] + (float)v1[1] + (float)v2[1] + (float)v3[1];
    a2 += (float)v0[2] + (float)v1[2] + (float)v2[2] + (float)v3[2];
    a3 += (float)v0[3] + (float)v1[3] + (float)v2[3] + (float)v3[3];
    c0 += (float)v4[0] + (float)v5[0] + (float)v6[0] + (float)v7[0];
    c1 += (float)v4[1] + (float)v5[1] + (float)v6[1] + (float)v7[1];
    c2 += (float)v4[2] + (float)v5[2] + (float)v6[2] + (float)v7[2];
    c3 += (float)v4[3] + (float)v5[3] + (float)v6[3] + (float)v7[3];
  }
  for (; e + 1 < e1; e += 2) {
    int s0 = col[e], s1 = col[e + 1];
    half4 v0 = xp[(size_t)s0 * 64 + lane];
    half4 v1 = xp[(size_t)s1 * 64 + lane];
    a0 += (float)v0[0]; a1 += (float)v0[1];
    a2 += (float)v0[2]; a3 += (float)v0[3];
    c0 += (float)v1[0]; c1 += (float)v1[1];
    c2 += (float)v1[2]; c3 += (float)v1[3];
  }
  if (e < e1) {
    int s0 = col[e];
    half4 v0 = xp[(size_t)s0 * 64 + lane];
    a0 += (float)v0[0]; a1 += (float)v0[1];
    a2 += (float)v0[2]; a3 += (float)v0[3];
  }
  half4 r;
  r[0] = (_Float16)(a0 + c0);
  r[1] = (_Float16)(a1 + c1);
  r[2] = (_Float16)(a2 + c2);
  r[3] = (_Float16)(a3 + c3);
  ((half4*)h)[(size_t)node * 64 + lane] = r;
}

// ---- merged weight pre-pack: both layers in one dispatch (128 blocks) ----
__global__ void pack2_k(const float* __restrict__ W1_0, const float* __restrict__ W2_0,
                        const float* __restrict__ W1_1, const float* __restrict__ W2_1,
                        _Float16* __restrict__ dst0, _Float16* __restrict__ dst1) {
  int layer = blockIdx.x >> 6;
  const float* W1 = layer ? W1_1 : W1_0;
  const float* W2 = layer ? W2_1 : W2_0;
  _Float16* dst = layer ? dst1 : dst0;
  int tid = (blockIdx.x & 63) * 256 + threadIdx.x;  // 0..16383
  if (tid >= 16384) return;
  int l = tid & 63;
  int g = (tid >> 6) & 7;
  int c = (tid >> 9) & 15;
  int isW2 = tid >> 13;
  int lg = l >> 4, l15 = l & 15;
  _Float16* o;
  if (!isW2) {
    int jt = g >> 2, ks = g & 3;
    int k0 = ks * 32 + lg * 8;
    int n = c * 32 + jt * 16 + l15;
    o = dst + (size_t)c * 8192 + g * 512 + l * 8;
#pragma unroll
    for (int i = 0; i < 8; ++i) o[i] = (_Float16)W1[(size_t)(k0 + i) * HDIM + n];
  } else {
    int k0 = c * 32 + lg * 8;
    int n = g * 16 + l15;
    o = dst + (size_t)c * 8192 + 4096 + g * 512 + l * 8;
#pragma unroll
    for (int i = 0; i < 8; ++i) o[i] = (_Float16)W2[(size_t)(k0 + i) * CDIM + n];
  }
}

// ---------------- fused MLP: LDS-shared W, double-buffered staging ----------
template <typename OT, bool REMAP>
__global__ __launch_bounds__(256, 4) void mlp_v3(
    const _Float16* __restrict__ hin, const _Float16* __restrict__ wpk,
    const float* __restrict__ b1, const float* __restrict__ b2,
    OT* __restrict__ out) {
  __shared__ alignas(16) _Float16 wbuf[2][8192];
  __shared__ alignas(16) _Float16 tbuf[4][32 * 32];

  const int tidx = threadIdx.x;
  const int lane = tidx & 63;
  const int wid = tidx >> 6;
  const int l15 = lane & 15, lg = lane >> 4;
  const long long r0 = (long long)blockIdx.x * 128 + wid * 32;

  half8 A[2][4];
#pragma unroll
  for (int rt = 0; rt < 2; ++rt) {
    long long row = r0 + rt * 16 + l15;
    if (row >= ROWS) row = ROWS - 1;
    const _Float16* hp = hin + row * CDIM + lg * 8;
#pragma unroll
    for (int ks = 0; ks < 4; ++ks) A[rt][ks] = *(const half8*)(hp + ks * 32);
  }

  {
    const _Float16* src = wpk;
#pragma unroll
    for (int q = 0; q < 4; ++q) {
      int s = wid * 4 + q;
      GLOAD_LDS16(src + s * 512 + lane * 8, &wbuf[0][s * 512]);
    }
  }
  __syncthreads();

  f32x4 acc[2][8];
#pragma unroll
  for (int rt = 0; rt < 2; ++rt)
#pragma unroll
    for (int ct = 0; ct < 8; ++ct) acc[rt][ct] = (f32x4){0.f, 0.f, 0.f, 0.f};

  _Float16* tw = &tbuf[wid][0];

  for (int c = 0; c < 16; ++c) {
    const int cur = c & 1;
    if (c + 1 < 16) {
      const _Float16* src = wpk + (size_t)(c + 1) * 8192;
#pragma unroll
      for (int q = 0; q < 4; ++q) {
        int s = wid * 4 + q;
        GLOAD_LDS16(src + s * 512 + lane * 8, &wbuf[cur ^ 1][s * 512]);
      }
    }
    const _Float16* w1c = &wbuf[cur][0];
    const _Float16* w2c = &wbuf[cur][4096];

#pragma unroll
    for (int jt = 0; jt < 2; ++jt) {
      f32x4 t0 = (f32x4){0.f, 0.f, 0.f, 0.f};
      f32x4 t1 = (f32x4){0.f, 0.f, 0.f, 0.f};
#pragma unroll
      for (int ks = 0; ks < 4; ++ks) {
        half8 b = *(const half8*)(w1c + (jt * 4 + ks) * 512 + lane * 8);
        t0 = mfma_f16(A[0][ks], b, t0);
        t1 = mfma_f16(A[1][ks], b, t1);
      }
      float bb = b1[c * 32 + jt * 16 + l15];
      int j = jt * 16 + l15;
#pragma unroll
      for (int r = 0; r < 4; ++r) {
        int n0 = lg * 4 + r;
        tw[n0 * 32 + (j ^ (((n0 >> 2) & 3) << 3))] = (_Float16)fmaxf(t0[r] + bb, 0.f);
        int n1 = 16 + lg * 4 + r;
        tw[n1 * 32 + (j ^ (((n1 >> 2) & 3) << 3))] = (_Float16)fmaxf(t1[r] + bb, 0.f);
      }
    }

    half8 ta0, ta1;
    {
      int n = l15;
      ta0 = *(const half8*)(tw + n * 32 + ((lg * 8) ^ (((n >> 2) & 3) << 3)));
      n = 16 + l15;
      ta1 = *(const half8*)(tw + n * 32 + ((lg * 8) ^ (((n >> 2) & 3) << 3)));
    }
#pragma unroll
    for (int ct = 0; ct < 8; ++ct) {
      half8 b = *(const half8*)(w2c + ct * 512 + lane * 8);
      acc[0][ct] = mfma_f16(ta0, b, acc[0][ct]);
      acc[1][ct] = mfma_f16(ta1, b, acc[1][ct]);
    }
    __syncthreads();
  }

#pragma unroll
  for (int ct = 0; ct < 8; ++ct) {
    float b2v = b2[ct * 16 + l15];
#pragma unroll
    for (int rt = 0; rt < 2; ++rt) {
#pragma unroll
      for (int r = 0; r < 4; ++r) {
        long long g = r0 + rt * 16 + lg * 4 + r;
        if (g < ROWS) {
          size_t off;
          if (REMAP) {
            off = (size_t)(g & 1) * NNODES * CDIM + (size_t)(g >> 1) * CDIM + ct * 16 + l15;
          } else {
            off = (size_t)g * CDIM + ct * 16 + l15;
          }
          out[off] = (OT)(acc[rt][ct][r] + b2v);
        }
      }
    }
  }
}

extern "C" void kernel_launch(void* const* d_in, const int* in_sizes, int n_in,
                              void* d_out, int out_size, void* d_ws, size_t ws_size,
                              hipStream_t stream) {
  const float* x0 = (const float*)d_in[0];
  const int* ei = (const int*)d_in[1];
  const float* W1_0 = (const float*)d_in[2];
  const float* b1_0 = (const float*)d_in[3];
  const float* W2_0 = (const float*)d_in[4];
  const float* b2_0 = (const float*)d_in[5];
  const float* W1_1 = (const float*)d_in[6];
  const float* b1_1 = (const float*)d_in[7];
  const float* W2_1 = (const float*)d_in[8];
  const float* b2_1 = (const float*)d_in[9];
  float* out = (float*)d_out;

  // workspace layout
  _Float16* xh = (_Float16*)d_ws;                  // ROWS*CDIM interleaved (25.6 MB)
  _Float16* hh = xh + (size_t)ROWS * CDIM;         // ROWS*CDIM interleaved (25.6 MB)
  _Float16* wpk0 = hh + (size_t)ROWS * CDIM;       // 131072 halfs
  _Float16* wpk1 = wpk0 + 131072;                  // 131072 halfs
  int* counts = (int*)(wpk1 + 131072);             // N
  int* offsets = counts + NNODES;                  // N+1
  int* cursor = offsets + NNODES + 1;              // N
  int* col = cursor + NNODES;                      // E
  int* bsum = col + NEDGES;                        // 16

  const int aggBlocks = (NNODES + 3) / 4;    // 12500
  const int mlpBlocks = (ROWS + 127) / 128;  // 782

  // CSR build + cvt (merged dispatches)
  hipMemsetAsync(counts, 0, NNODES * sizeof(int), stream);
  histcvt_k<<<EBLOCKS + CVTBLOCKS, 256, 0, stream>>>(ei, counts, x0, xh);
  scan1_k<<<SC_BLOCKS, 256, 0, stream>>>(counts, bsum);
  scan23_k<<<SC_BLOCKS, 256, 0, stream>>>(counts, bsum, offsets, cursor);
  fill_k<<<EBLOCKS, 256, 0, stream>>>(ei, cursor, col);

  // weight pre-pack (both layers, one dispatch)
  pack2_k<<<128, 256, 0, stream>>>(W1_0, W2_0, W1_1, W2_1, wpk0, wpk1);

  // layer 0
  aggi_k<<<aggBlocks, 256, 0, stream>>>(xh, offsets, col, hh);
  mlp_v3<_Float16, false><<<mlpBlocks, 256, 0, stream>>>(hh, wpk0, b1_0, b2_0, xh);
  // layer 1
  aggi_k<<<aggBlocks, 256, 0, stream>>>(xh, offsets, col, hh);
  mlp_v3<float, true><<<mlpBlocks, 256, 0, stream>>>(hh, wpk1, b1_1, b2_1, out);
}